// Round 9
// baseline (83.656 us; speedup 1.0000x reference)
//
#include <hip/hip_runtime.h>
#include <math.h>

#define NODES   100000
#define DIM     128
#define NEDGES  1600000          // 4 * 400000
#define NQUADS  (NEDGES / 4)     // 400000
#define NGROUPS (NODES / 8)      // 12500 32-lane groups, 8 nodes each

#define LOG2E 1.44269504088896340736f

// clang-native vector types (accepted by __builtin_nontemporal_*)
typedef int   v4i __attribute__((ext_vector_type(4)));
typedef float v4f __attribute__((ext_vector_type(4)));

__device__ __forceinline__ float fast_sigmoid(float x) {
    return __builtin_amdgcn_rcpf(1.0f + __builtin_amdgcn_exp2f(-x * LOG2E));
}

__device__ __forceinline__ float dot4(v4f a, v4f b) {
    return a.x * b.x + a.y * b.y + a.z * b.z + a.w * b.w;
}

// Phase 1: identical to R8 (32 lanes/node, 8 nodes/thread, ILP=8).
__global__ __launch_bounds__(256) void node_proj_kernel(
    const float* __restrict__ h,
    const float* __restrict__ W,      // 256 floats: Wu | Wv
    const float* __restrict__ bias_ptr,
    float* __restrict__ pu,
    float* __restrict__ pv)
{
    const int tid  = blockIdx.x * 256 + threadIdx.x;
    const int lane = tid & 31;
    const int grp  = tid >> 5;
    if (grp >= NGROUPS) return;
    const int n0 = grp * 8;

    const v4f wu = *reinterpret_cast<const v4f*>(W + lane * 4);
    const v4f wv = *reinterpret_cast<const v4f*>(W + DIM + lane * 4);
    const float b = bias_ptr[0];

    const float* hb = h + (size_t)n0 * DIM + lane * 4;
    v4f hr[8];
    #pragma unroll
    for (int j = 0; j < 8; ++j)
        hr[j] = *reinterpret_cast<const v4f*>(hb + j * DIM);

    float su[8], sv[8];
    #pragma unroll
    for (int j = 0; j < 8; ++j) {
        su[j] = dot4(hr[j], wu);
        sv[j] = dot4(hr[j], wv);
    }

    #pragma unroll
    for (int off = 16; off >= 1; off >>= 1) {
        #pragma unroll
        for (int j = 0; j < 8; ++j) {
            su[j] += __shfl_xor(su[j], off);
            sv[j] += __shfl_xor(sv[j], off);
        }
    }

    if (lane == 0) {
        v4f a0 = { su[0], su[1], su[2], su[3] };
        v4f a1 = { su[4], su[5], su[6], su[7] };
        v4f b0 = { sv[0] + b, sv[1] + b, sv[2] + b, sv[3] + b };
        v4f b1 = { sv[4] + b, sv[5] + b, sv[6] + b, sv[7] + b };
        *reinterpret_cast<v4f*>(pu + n0)     = a0;
        *reinterpret_cast<v4f*>(pu + n0 + 4) = a1;
        *reinterpret_cast<v4f*>(pv + n0)     = b0;
        *reinterpret_cast<v4f*>(pv + n0 + 4) = b1;
    }
}

// Phase 2 (INSTRUMENTED: body repeated `reps` times; `zero`==0 at runtime but
// opaque to LLVM, so index/load/store chains re-execute fully each rep and the
// marginal bench delta = one steady-state phase-2 execution). Inner body is
// byte-identical to R8's phase 2. Output identical to running once.
__global__ __launch_bounds__(256) void edge_score_kernel(
    const int*   __restrict__ src,
    const int*   __restrict__ dst,
    const float* __restrict__ pu,
    const float* __restrict__ pv,
    float* __restrict__ out,
    int reps, int zero)
{
    int i = blockIdx.x * 256 + threadIdx.x;
    if (i >= NQUADS) return;

    for (int rep = 0; rep < reps; ++rep) {
        int i2 = i + rep * zero;     // == i at runtime; opaque to the compiler

        v4i s4 = reinterpret_cast<const v4i*>(src)[i2];
        v4i d4 = reinterpret_cast<const v4i*>(dst)[i2];

        float a0 = pu[s4.x], b0 = pv[d4.x];
        float a1 = pu[s4.y], b1 = pv[d4.y];
        float a2 = pu[s4.z], b2 = pv[d4.z];
        float a3 = pu[s4.w], b3 = pv[d4.w];

        v4f r;
        r.x = fast_sigmoid(a0 + b0);
        r.y = fast_sigmoid(a1 + b1);
        r.z = fast_sigmoid(a2 + b2);
        r.w = fast_sigmoid(a3 + b3);

        __builtin_nontemporal_store(r, reinterpret_cast<v4f*>(out) + i2);
    }
}

extern "C" void kernel_launch(void* const* d_in, const int* in_sizes, int n_in,
                              void* d_out, int out_size, void* d_ws, size_t ws_size,
                              hipStream_t stream) {
    const float* h    = (const float*)d_in[0];
    const int*   src  = (const int*)d_in[1];
    const int*   dst  = (const int*)d_in[2];
    const float* W    = (const float*)d_in[3];   // (1, 256)
    const float* bias = (const float*)d_in[4];   // (1,)
    float* out = (float*)d_out;

    float* pu = (float*)d_ws;                    // NODES floats
    float* pv = pu + NODES;                      // NODES floats

    const int reps = 5;                          // instrumentation: 1 real + 4 extra
    const int zero = in_sizes[4] - 1;            // bias has 1 element -> 0, opaque

    node_proj_kernel<<<(NGROUPS * 32 + 255) / 256, 256, 0, stream>>>(h, W, bias, pu, pv);
    edge_score_kernel<<<(NQUADS + 255) / 256, 256, 0, stream>>>(src, dst, pu, pv, out, reps, zero);
}

// Round 10
// 29.560 us; speedup vs baseline: 2.8301x; 2.8301x over previous
//
#include <hip/hip_runtime.h>
#include <math.h>

#define NODES   100000
#define DIM     128
#define NEDGES  1600000          // 4 * 400000; == 6250 * 256 exactly
#define NGROUPS (NODES / 8)      // 12500 32-lane groups, 8 nodes each

#define LOG2E 1.44269504088896340736f

// clang-native vector types
typedef int      v4i  __attribute__((ext_vector_type(4)));
typedef uint32_t v4u  __attribute__((ext_vector_type(4)));
typedef float    v4f  __attribute__((ext_vector_type(4)));
typedef _Float16 h2   __attribute__((ext_vector_type(2)));

__device__ __forceinline__ float fast_sigmoid(float x) {
    return __builtin_amdgcn_rcpf(1.0f + __builtin_amdgcn_exp2f(-x * LOG2E));
}

__device__ __forceinline__ float dot4(v4f a, v4f b) {
    return a.x * b.x + a.y * b.y + a.z * b.z + a.w * b.w;
}

// Phase 1: p[n] = pack_f16x2( h[n].Wu , h[n].Wv + bias ).
// Structure identical to R8 (32 lanes/node, 8 nodes/thread, ILP=8); output is
// now ONE 400 KB packed-f16 table instead of two f32 tables -> halves phase-2
// table footprint (cold-start L3 fills halve, L1 hit odds double).
// f16 RTZ error: |p| <~ 4, rel 2^-10 -> abs ~4e-3 per term, sigmoid slope 0.25
// -> output err ~2e-3 << 2e-2 threshold.
__global__ __launch_bounds__(256) void node_proj_kernel(
    const float* __restrict__ h,
    const float* __restrict__ W,      // 256 floats: Wu | Wv
    const float* __restrict__ bias_ptr,
    uint32_t* __restrict__ p)
{
    const int tid  = blockIdx.x * 256 + threadIdx.x;
    const int lane = tid & 31;
    const int grp  = tid >> 5;
    if (grp >= NGROUPS) return;
    const int n0 = grp * 8;

    const v4f wu = *reinterpret_cast<const v4f*>(W + lane * 4);
    const v4f wv = *reinterpret_cast<const v4f*>(W + DIM + lane * 4);
    const float b = bias_ptr[0];

    const float* hb = h + (size_t)n0 * DIM + lane * 4;
    v4f hr[8];
    #pragma unroll
    for (int j = 0; j < 8; ++j)
        hr[j] = *reinterpret_cast<const v4f*>(hb + j * DIM);

    float su[8], sv[8];
    #pragma unroll
    for (int j = 0; j < 8; ++j) {
        su[j] = dot4(hr[j], wu);
        sv[j] = dot4(hr[j], wv);
    }

    #pragma unroll
    for (int off = 16; off >= 1; off >>= 1) {
        #pragma unroll
        for (int j = 0; j < 8; ++j) {
            su[j] += __shfl_xor(su[j], off);
            sv[j] += __shfl_xor(sv[j], off);
        }
    }

    if (lane == 0) {
        uint32_t w[8];
        #pragma unroll
        for (int j = 0; j < 8; ++j) {
            // low half = pu, high half = pv (+bias); RTZ pack, 1 VALU op.
            w[j] = __builtin_bit_cast(uint32_t,
                       __builtin_amdgcn_cvt_pkrtz(su[j], sv[j] + b));
        }
        v4u w0 = { w[0], w[1], w[2], w[3] };
        v4u w1 = { w[4], w[5], w[6], w[7] };
        *reinterpret_cast<v4u*>(p + n0)     = w0;
        *reinterpret_cast<v4u*>(p + n0 + 4) = w1;
    }
}

// Phase 2: out[e] = sigmoid( f16lo(p[src[e]]) + f16hi(p[dst[e]]) ).
// 1 edge/thread (max TLP, smooth tail), coalesced dword index loads and
// NT dword store; the 2 divergent gathers per edge are the HW floor
// (~2.5 cyc/gather-lane L1-miss pipeline, R9 instrumentation).
__global__ __launch_bounds__(256) void edge_score_kernel(
    const int*      __restrict__ src,
    const int*      __restrict__ dst,
    const uint32_t* __restrict__ p,
    float* __restrict__ out)
{
    const int i = blockIdx.x * 256 + threadIdx.x;   // grid is exact: 6250*256 == NEDGES

    const int s = src[i];
    const int d = dst[i];

    const uint32_t ws = p[s];
    const uint32_t wd = p[d];

    const float a = (float)__builtin_bit_cast(h2, ws).x;   // pu[s]
    const float c = (float)__builtin_bit_cast(h2, wd).y;   // pv[d] (+bias)

    __builtin_nontemporal_store(fast_sigmoid(a + c), out + i);
}

extern "C" void kernel_launch(void* const* d_in, const int* in_sizes, int n_in,
                              void* d_out, int out_size, void* d_ws, size_t ws_size,
                              hipStream_t stream) {
    const float* h    = (const float*)d_in[0];
    const int*   src  = (const int*)d_in[1];
    const int*   dst  = (const int*)d_in[2];
    const float* W    = (const float*)d_in[3];   // (1, 256)
    const float* bias = (const float*)d_in[4];   // (1,)
    float* out = (float*)d_out;

    uint32_t* p = (uint32_t*)d_ws;               // NODES packed f16x2 entries (400 KB)

    // Phase 1: 32 lanes/node, 8 nodes/thread -> 400k threads -> 1563 blocks.
    node_proj_kernel<<<(NGROUPS * 32 + 255) / 256, 256, 0, stream>>>(h, W, bias, p);

    // Phase 2: 1 edge/thread -> 1.6M threads -> 6250 blocks (exact).
    edge_score_kernel<<<NEDGES / 256, 256, 0, stream>>>(src, dst, p, out);
}